// Round 1
// baseline (2151.799 us; speedup 1.0000x reference)
//
#include <hip/hip_runtime.h>

#define BB 64
#define TT 4096
#define KK 48
#define CHUNK 64
#define NCHUNK (TT / CHUNK)

__device__ __forceinline__ float fexp(float x) {
    return __builtin_amdgcn_exp2f(x * 1.4426950408889634f);
}
__device__ __forceinline__ float flog(float x) {
    return __builtin_amdgcn_logf(x) * 0.6931471805599453f;
}

__global__ void zero_out_kernel(float* out) {
    if (threadIdx.x < BB) out[threadIdx.x] = 0.0f;
}

// One block per (b, 256-step tile). Computes point score + transition score,
// atomically subtracts into out[b] (out[b] = log_norm - target).
__global__ __launch_bounds__(256) void scores_kernel(
    const float* __restrict__ y_true, const float* __restrict__ y_pred,
    const float* __restrict__ trans, float* __restrict__ out) {
    const int b = blockIdx.y;
    const int t0 = blockIdx.x * 256;
    const int tid = threadIdx.x;
    const int t = t0 + tid;

    __shared__ int lab_s[257];
    __shared__ float msk_s[257];

    const size_t base = ((size_t)b * TT + t) * KK;
    float dot = 0.0f;
    int lab = 0;
    bool ok = true;
#pragma unroll
    for (int i = 0; i < KK; i += 4) {
        float4 a = *(const float4*)(y_true + base + i);
        float4 p = *(const float4*)(y_pred + base + i);
        dot += a.x * p.x + a.y * p.y + a.z * p.z + a.w * p.w;
        if (a.x > 0.5f) lab = i;
        if (a.y > 0.5f) lab = i + 1;
        if (a.z > 0.5f) lab = i + 2;
        if (a.w > 0.5f) lab = i + 3;
        ok = ok && (p.x > -1e6f) && (p.y > -1e6f) && (p.z > -1e6f) && (p.w > -1e6f);
    }
    lab_s[tid] = lab;
    msk_s[tid] = ok ? 1.0f : 0.0f;

    // boundary element t0+256 (needed by tid==255 for the transition term)
    if (tid == 0 && t0 + 256 < TT) {
        const size_t be = ((size_t)b * TT + t0 + 256) * KK;
        int labe = 0;
        bool oke = true;
#pragma unroll
        for (int i = 0; i < KK; i += 4) {
            float4 a = *(const float4*)(y_true + be + i);
            float4 p = *(const float4*)(y_pred + be + i);
            if (a.x > 0.5f) labe = i;
            if (a.y > 0.5f) labe = i + 1;
            if (a.z > 0.5f) labe = i + 2;
            if (a.w > 0.5f) labe = i + 3;
            oke = oke && (p.x > -1e6f) && (p.y > -1e6f) && (p.z > -1e6f) && (p.w > -1e6f);
        }
        lab_s[256] = labe;
        msk_s[256] = oke ? 1.0f : 0.0f;
    }
    __syncthreads();

    const float m = msk_s[tid];
    float contrib = m * dot;
    if (t < TT - 1) {
        contrib += m * msk_s[tid + 1] * trans[lab * KK + lab_s[tid + 1]];
    }
    // wave reduction, then one atomic per wave
#pragma unroll
    for (int off = 32; off; off >>= 1) contrib += __shfl_xor(contrib, off);
    if ((tid & 63) == 0) atomicAdd(&out[b], -contrib);
}

// One block per batch element. Wave 0 runs the sequential forward scan with
// lane j owning state s[j] and E-column exp(trans[:,j]) in registers.
// Waves 1..3 double-buffer x tiles into LDS.
__global__ __launch_bounds__(256) void scan_kernel(
    const float* __restrict__ y_pred, const float* __restrict__ trans,
    float* __restrict__ out) {
    const int b = blockIdx.x;
    const int tid = threadIdx.x;
    const int wave = tid >> 6;
    const int lane = tid & 63;
    const int jj = (lane < KK) ? lane : 0;

    __shared__ float xbuf[2][CHUNK * KK];  // 2 x 12 KB

    const float* xp = y_pred + (size_t)b * TT * KK;

    // load chunk 0 (all threads)
    for (int q = tid; q < CHUNK * KK / 4; q += 256)
        ((float4*)xbuf[0])[q] = ((const float4*)xp)[q];

    // wave 0: preload exp(trans) column jj (48 VGPRs)
    float ebcol[KK];
    float s = 0.0f;
    if (wave == 0) {
#pragma unroll
        for (int i = 0; i < KK; i++) ebcol[i] = fexp(trans[i * KK + jj]);
    }
    __syncthreads();

    for (int c = 0; c < NCHUNK; c++) {
        if (wave > 0) {
            if (c + 1 < NCHUNK) {
                const float4* src = (const float4*)(xp + (size_t)(c + 1) * CHUNK * KK);
                float4* dst = (float4*)xbuf[(c + 1) & 1];
                for (int q = tid - 64; q < CHUNK * KK / 4; q += 192) dst[q] = src[q];
            }
        } else {
            const float* xc = xbuf[c & 1];
            int tt = 0;
            if (c == 0) {
                // init: s = mask_0 * y_pred[b,0,:]
                float x0 = xc[jj];
                bool okl = (lane >= KK) || (x0 > -1e6f);
                unsigned long long bal = __ballot(okl);
                float m0 = (bal == ~0ull) ? 1.0f : 0.0f;
                s = (lane < KK) ? m0 * x0 : 0.0f;
                tt = 1;
            }
            for (; tt < CHUNK; tt++) {
                float xj = xc[tt * KK + jj];
                bool okl = (lane >= KK) || (xj > -1e6f);
                bool m = (__ballot(okl) == ~0ull);
                float C = __shfl(s, 0);
                float e = fexp(s - C);
                float a0 = 0.f, a1 = 0.f, a2 = 0.f, a3 = 0.f;
#pragma unroll
                for (int i = 0; i < KK; i += 4) {
                    a0 += __shfl(e, i + 0) * ebcol[i + 0];
                    a1 += __shfl(e, i + 1) * ebcol[i + 1];
                    a2 += __shfl(e, i + 2) * ebcol[i + 2];
                    a3 += __shfl(e, i + 3) * ebcol[i + 3];
                }
                float acc = (a0 + a1) + (a2 + a3);
                float nv = C + flog(acc) + xj;
                if (m && lane < KK) s = nv;
            }
        }
        __syncthreads();
    }

    if (wave == 0) {
        float C = __shfl(s, 0);
        float e = (lane < KK) ? fexp(s - C) : 0.0f;
#pragma unroll
        for (int off = 32; off; off >>= 1) e += __shfl_xor(e, off);
        if (lane == 0) atomicAdd(&out[b], C + flog(e));
    }
}

extern "C" void kernel_launch(void* const* d_in, const int* in_sizes, int n_in,
                              void* d_out, int out_size, void* d_ws, size_t ws_size,
                              hipStream_t stream) {
    const float* y_true = (const float*)d_in[0];
    const float* y_pred = (const float*)d_in[1];
    const float* trans = (const float*)d_in[2];
    float* out = (float*)d_out;

    zero_out_kernel<<<1, 64, 0, stream>>>(out);
    scores_kernel<<<dim3(TT / 256, BB), 256, 0, stream>>>(y_true, y_pred, trans, out);
    scan_kernel<<<BB, 256, 0, stream>>>(y_pred, trans, out);
}

// Round 2
// 1066.965 us; speedup vs baseline: 2.0167x; 2.0167x over previous
//
#include <hip/hip_runtime.h>

#define BB 64
#define TT 4096
#define KK 48
#define CHUNK 64
#define NCHUNK (TT / CHUNK)

__device__ __forceinline__ float fexp(float x) {
    return __builtin_amdgcn_exp2f(x * 1.4426950408889634f);
}
__device__ __forceinline__ float flog(float x) {
    return __builtin_amdgcn_logf(x) * 0.6931471805599453f;
}
__device__ __forceinline__ float rdlane(float v, int lane) {
    return __int_as_float(__builtin_amdgcn_readlane(__float_as_int(v), lane));
}

__global__ void zero_out_kernel(float* out) {
    if (threadIdx.x < BB) out[threadIdx.x] = 0.0f;
}

// One block per (b, 256-step tile). Computes point score + transition score,
// atomically subtracts into out[b] (out[b] = log_norm - target).
__global__ __launch_bounds__(256) void scores_kernel(
    const float* __restrict__ y_true, const float* __restrict__ y_pred,
    const float* __restrict__ trans, float* __restrict__ out) {
    const int b = blockIdx.y;
    const int t0 = blockIdx.x * 256;
    const int tid = threadIdx.x;
    const int t = t0 + tid;

    __shared__ int lab_s[257];
    __shared__ float msk_s[257];

    const size_t base = ((size_t)b * TT + t) * KK;
    float dot = 0.0f;
    int lab = 0;
    bool ok = true;
#pragma unroll
    for (int i = 0; i < KK; i += 4) {
        float4 a = *(const float4*)(y_true + base + i);
        float4 p = *(const float4*)(y_pred + base + i);
        dot += a.x * p.x + a.y * p.y + a.z * p.z + a.w * p.w;
        if (a.x > 0.5f) lab = i;
        if (a.y > 0.5f) lab = i + 1;
        if (a.z > 0.5f) lab = i + 2;
        if (a.w > 0.5f) lab = i + 3;
        ok = ok && (p.x > -1e6f) && (p.y > -1e6f) && (p.z > -1e6f) && (p.w > -1e6f);
    }
    lab_s[tid] = lab;
    msk_s[tid] = ok ? 1.0f : 0.0f;

    // boundary element t0+256 (needed by tid==255 for the transition term)
    if (tid == 0 && t0 + 256 < TT) {
        const size_t be = ((size_t)b * TT + t0 + 256) * KK;
        int labe = 0;
        bool oke = true;
#pragma unroll
        for (int i = 0; i < KK; i += 4) {
            float4 a = *(const float4*)(y_true + be + i);
            float4 p = *(const float4*)(y_pred + be + i);
            if (a.x > 0.5f) labe = i;
            if (a.y > 0.5f) labe = i + 1;
            if (a.z > 0.5f) labe = i + 2;
            if (a.w > 0.5f) labe = i + 3;
            oke = oke && (p.x > -1e6f) && (p.y > -1e6f) && (p.z > -1e6f) && (p.w > -1e6f);
        }
        lab_s[256] = labe;
        msk_s[256] = oke ? 1.0f : 0.0f;
    }
    __syncthreads();

    const float m = msk_s[tid];
    float contrib = m * dot;
    if (t < TT - 1) {
        contrib += m * msk_s[tid + 1] * trans[lab * KK + lab_s[tid + 1]];
    }
    // wave reduction, then one atomic per wave
#pragma unroll
    for (int off = 32; off; off >>= 1) contrib += __shfl_xor(contrib, off);
    if ((tid & 63) == 0) atomicAdd(&out[b], -contrib);
}

// One block per batch element. Wave 0 runs the sequential forward scan with
// lane j owning state s[j] and E-column exp(trans[:,j]) in registers.
// Broadcast of e across lanes via v_readlane (VALU pipe, no LDS round-trip).
// Waves 1..3 double-buffer x tiles into LDS.
__global__ __launch_bounds__(256) void scan_kernel(
    const float* __restrict__ y_pred, const float* __restrict__ trans,
    float* __restrict__ out) {
    const int b = blockIdx.x;
    const int tid = threadIdx.x;
    const int wave = tid >> 6;
    const int lane = tid & 63;
    const int jj = (lane < KK) ? lane : 0;

    __shared__ float xbuf[2][CHUNK * KK];  // 2 x 12 KB

    const float* xp = y_pred + (size_t)b * TT * KK;

    // load chunk 0 (all threads)
    for (int q = tid; q < CHUNK * KK / 4; q += 256)
        ((float4*)xbuf[0])[q] = ((const float4*)xp)[q];

    // wave 0: preload exp(trans) column jj (48 VGPRs)
    float ebcol[KK];
    float s = 0.0f;
    if (wave == 0) {
#pragma unroll
        for (int i = 0; i < KK; i++) ebcol[i] = fexp(trans[i * KK + jj]);
    }
    __syncthreads();

    for (int c = 0; c < NCHUNK; c++) {
        if (wave > 0) {
            if (c + 1 < NCHUNK) {
                const float4* src = (const float4*)(xp + (size_t)(c + 1) * CHUNK * KK);
                float4* dst = (float4*)xbuf[(c + 1) & 1];
                for (int q = tid - 64; q < CHUNK * KK / 4; q += 192) dst[q] = src[q];
            }
        } else {
            const float* xc = xbuf[c & 1];
            int tt = 0;
            if (c == 0) {
                // init: s = mask_0 * y_pred[b,0,:]
                float x0 = xc[jj];
                bool okl = (lane >= KK) || (x0 > -1e6f);
                unsigned long long bal = __ballot(okl);
                float m0 = (bal == ~0ull) ? 1.0f : 0.0f;
                s = (lane < KK) ? m0 * x0 : 0.0f;
                tt = 1;
            }
            // software-pipelined x load: xj for step tt fetched one step ahead
            float xj = xc[tt * KK + jj];
            for (; tt < CHUNK; tt++) {
                // prefetch next step's x while this step's matvec runs
                int tn = (tt + 1 < CHUNK) ? tt + 1 : tt;
                float xnext = xc[tn * KK + jj];

                bool okl = (lane >= KK) || (xj > -1e6f);
                bool m = (__ballot(okl) == ~0ull);
                float C = rdlane(s, 0);
                float e = fexp(s - C);
                float a0 = 0.f, a1 = 0.f, a2 = 0.f, a3 = 0.f;
#pragma unroll
                for (int i = 0; i < KK; i += 4) {
                    a0 = fmaf(rdlane(e, i + 0), ebcol[i + 0], a0);
                    a1 = fmaf(rdlane(e, i + 1), ebcol[i + 1], a1);
                    a2 = fmaf(rdlane(e, i + 2), ebcol[i + 2], a2);
                    a3 = fmaf(rdlane(e, i + 3), ebcol[i + 3], a3);
                }
                float acc = (a0 + a1) + (a2 + a3);
                float nv = C + flog(acc) + xj;
                if (m && lane < KK) s = nv;
                xj = xnext;
            }
        }
        __syncthreads();
    }

    if (wave == 0) {
        float C = rdlane(s, 0);
        float e = (lane < KK) ? fexp(s - C) : 0.0f;
#pragma unroll
        for (int off = 32; off; off >>= 1) e += __shfl_xor(e, off);
        if (lane == 0) atomicAdd(&out[b], C + flog(e));
    }
}

extern "C" void kernel_launch(void* const* d_in, const int* in_sizes, int n_in,
                              void* d_out, int out_size, void* d_ws, size_t ws_size,
                              hipStream_t stream) {
    const float* y_true = (const float*)d_in[0];
    const float* y_pred = (const float*)d_in[1];
    const float* trans = (const float*)d_in[2];
    float* out = (float*)d_out;

    zero_out_kernel<<<1, 64, 0, stream>>>(out);
    scores_kernel<<<dim3(TT / 256, BB), 256, 0, stream>>>(y_true, y_pred, trans, out);
    scan_kernel<<<BB, 256, 0, stream>>>(y_pred, trans, out);
}

// Round 4
// 376.935 us; speedup vs baseline: 5.7087x; 2.8306x over previous
//
#include <hip/hip_runtime.h>

#define BB 64
#define TT 4096
#define KK 48
#define NSEG 16
#define SEGLEN 256          // 4 chunks of 64 steps
#define NCHUNK_SEG 4
#define UST 52              // Ubuf column stride in bf16 elems
#define XSTF 64             // exbuf row stride in floats

typedef __bf16 bf16_t;
typedef bf16_t bf16x8 __attribute__((ext_vector_type(8)));
typedef float f32x16 __attribute__((ext_vector_type(16)));

__device__ __forceinline__ float fexp(float x) {   // natural exp
    return __builtin_amdgcn_exp2f(x * 1.4426950408889634f);
}
__device__ __forceinline__ float flog2(float x) { return __builtin_amdgcn_logf(x); }
__device__ __forceinline__ float frcp(float x) { return __builtin_amdgcn_rcpf(x); }
__device__ __forceinline__ float rdlanef(float v, int l) {
    return __int_as_float(__builtin_amdgcn_readlane(__float_as_int(v), l));
}
__device__ __forceinline__ unsigned short bf16bits(float f) {
    return __builtin_bit_cast(unsigned short, (bf16_t)f);
}
__device__ __forceinline__ float bfbits2f(unsigned int u) {  // low 16 bits = bf16
    return __uint_as_float(u << 16);
}

__global__ void zero_out_kernel(float* out) {
    if (threadIdx.x < BB) out[threadIdx.x] = 0.0f;
}

// ---------------- scores: point + transition, subtracted into out[b] ----------------
__global__ __launch_bounds__(256) void scores_kernel(
    const float* __restrict__ y_true, const float* __restrict__ y_pred,
    const float* __restrict__ trans, float* __restrict__ out) {
    const int b = blockIdx.y;
    const int t0 = blockIdx.x * 256;
    const int tid = threadIdx.x;
    const int t = t0 + tid;

    __shared__ int lab_s[257];
    __shared__ float msk_s[257];

    const size_t base = ((size_t)b * TT + t) * KK;
    float dot = 0.0f, labf = 0.0f, pmin = 1e30f;
#pragma unroll
    for (int i = 0; i < KK; i += 4) {
        float4 a = *(const float4*)(y_true + base + i);
        float4 p = *(const float4*)(y_pred + base + i);
        dot = fmaf(a.x, p.x, dot); dot = fmaf(a.y, p.y, dot);
        dot = fmaf(a.z, p.z, dot); dot = fmaf(a.w, p.w, dot);
        labf = fmaf(a.x, (float)i, labf);     labf = fmaf(a.y, (float)(i + 1), labf);
        labf = fmaf(a.z, (float)(i + 2), labf); labf = fmaf(a.w, (float)(i + 3), labf);
        pmin = fminf(fminf(pmin, p.x), fminf(p.y, p.z));
        pmin = fminf(pmin, p.w);
    }
    lab_s[tid] = (int)(labf + 0.5f);
    msk_s[tid] = (pmin > -1e6f) ? 1.0f : 0.0f;

    if (tid == 0 && t0 + 256 < TT) {
        const size_t be = ((size_t)b * TT + t0 + 256) * KK;
        float lf = 0.0f, pm = 1e30f;
#pragma unroll
        for (int i = 0; i < KK; i += 4) {
            float4 a = *(const float4*)(y_true + be + i);
            float4 p = *(const float4*)(y_pred + be + i);
            lf = fmaf(a.x, (float)i, lf);     lf = fmaf(a.y, (float)(i + 1), lf);
            lf = fmaf(a.z, (float)(i + 2), lf); lf = fmaf(a.w, (float)(i + 3), lf);
            pm = fminf(fminf(pm, p.x), fminf(p.y, p.z));
            pm = fminf(pm, p.w);
        }
        lab_s[256] = (int)(lf + 0.5f);
        msk_s[256] = (pm > -1e6f) ? 1.0f : 0.0f;
    }
    __syncthreads();

    const float m = msk_s[tid];
    float contrib = m * dot;
    if (t < TT - 1) {
        contrib += m * msk_s[tid + 1] * trans[lab_s[tid] * KK + lab_s[tid + 1]];
    }
#pragma unroll
    for (int off = 32; off; off >>= 1) contrib += __shfl_xor(contrib, off);
    if ((tid & 63) == 0) atomicAdd(&out[b], -contrib);
}

// ---------------- stage 1: per-(b,segment) matrix product via MFMA ----------------
// U = Seg^T maintained in LDS (bf16), recurrence per step t:
//   U_new[a][c] = ex_t[a] * sum_k E^T[a][k] * U[k][c]
// SEGLEN=256 steps processed in 4 chunks of 64 (ballot + fp32 ex staging per chunk).
// Per step: rescale so stored U[0][0]==1; accumulate log2 scale in ls (exact).
__global__ __launch_bounds__(64) void stage1_kernel(
    const float* __restrict__ y_pred, const float* __restrict__ trans,
    bf16_t* __restrict__ ws_u, float* __restrict__ ws_ls) {
    const int s = blockIdx.x, b = blockIdx.y;
    const int lane = threadIdx.x;
    const int half = lane >> 5;
    const int l31 = lane & 31;

    __shared__ __align__(16) bf16_t Ubuf[64 * UST];
    __shared__ __align__(16) float exbuf[64 * XSTF];   // fp32 ex, 64 steps/chunk

    // A fragments: E^T (= exp(trans)^T), zero-padded, 3 ksteps of 16.
    // A[m][k]: m = l31 + 32*mt, k = ks*16 + half*8 + e
    bf16x8 afrag[2][3];
#pragma unroll
    for (int mt = 0; mt < 2; mt++) {
        int m = l31 + 32 * mt;
#pragma unroll
        for (int ks = 0; ks < 3; ks++) {
            bf16x8 f;
#pragma unroll
            for (int e = 0; e < 8; e++) {
                int k = ks * 16 + half * 8 + e;
                float v = (m < KK && k < KK) ? fexp(trans[k * KK + m]) : 0.0f;
                f[e] = (bf16_t)v;
            }
            afrag[mt][ks] = f;
        }
    }

    // init U = I
    {
        uint2* col = (uint2*)&Ubuf[lane * UST];
#pragma unroll
        for (int i = 0; i < 13; i++) col[i] = make_uint2(0, 0);
    }
    __syncthreads();
    if (lane < KK) Ubuf[lane * UST + lane] = (bf16_t)1.0f;

    f32x16 z16;
#pragma unroll
    for (int r = 0; r < 16; r++) z16[r] = 0.0f;

    float ls = 0.0f;
    for (int ch = 0; ch < NCHUNK_SEG; ch++) {
        const int t0 = s * SEGLEN + ch * 64;
        // lane = local timestep within chunk: load x row, mask, stage fp32 ex
        const float* xrow = y_pred + ((size_t)b * TT + t0 + lane) * KK;
        float xv[KK];
#pragma unroll
        for (int i = 0; i < KK; i += 4) {
            float4 p = *(const float4*)(xrow + i);
            xv[i] = p.x; xv[i + 1] = p.y; xv[i + 2] = p.z; xv[i + 3] = p.w;
        }
        float pmin = xv[0];
#pragma unroll
        for (int i = 1; i < KK; i++) pmin = fminf(pmin, xv[i]);
        unsigned long long maskbits = __ballot(pmin > -1e6f);

        __syncthreads();   // prior chunk's exbuf reads complete before overwrite
        // exbuf row `lane`, 4-float granules rotated by lane
#pragma unroll
        for (int g4 = 0; g4 < 16; g4++) {
            float4 val = make_float4(0.f, 0.f, 0.f, 0.f);
            if (g4 < 12) {
                val = make_float4(fexp(xv[4 * g4 + 0]), fexp(xv[4 * g4 + 1]),
                                  fexp(xv[4 * g4 + 2]), fexp(xv[4 * g4 + 3]));
            }
            int pos = (g4 + lane) & 15;
            *(float4*)&exbuf[lane * XSTF + pos * 4] = val;
        }
        __syncthreads();

        const int ttstart = (s == 0 && ch == 0) ? 1 : 0;
        for (int tt = ttstart; tt < 64; tt++) {
            if (!((maskbits >> tt) & 1ull)) continue;

            // B fragments from Ubuf: B[k][n], n = l31+32*nt, k = ks*16+half*8+e
            bf16x8 bfrag[3][2];
#pragma unroll
            for (int ks = 0; ks < 3; ks++)
#pragma unroll
                for (int nt = 0; nt < 2; nt++) {
                    int n = l31 + 32 * nt;
                    const bf16_t* p = &Ubuf[n * UST + ks * 16 + half * 8];
                    uint2 lo = *(const uint2*)p;
                    uint2 hi = *(const uint2*)(p + 4);
                    uint4 q = make_uint4(lo.x, lo.y, hi.x, hi.y);
                    bfrag[ks][nt] = __builtin_bit_cast(bf16x8, q);
                }

            f32x16 acc[4];
#pragma unroll
            for (int mt = 0; mt < 2; mt++)
#pragma unroll
                for (int nt = 0; nt < 2; nt++) {
                    f32x16 a0 = __builtin_amdgcn_mfma_f32_32x32x16_bf16(afrag[mt][0], bfrag[0][nt], z16, 0, 0, 0);
                    a0 = __builtin_amdgcn_mfma_f32_32x32x16_bf16(afrag[mt][1], bfrag[1][nt], a0, 0, 0, 0);
                    acc[mt * 2 + nt] = __builtin_amdgcn_mfma_f32_32x32x16_bf16(afrag[mt][2], bfrag[2][nt], a0, 0, 0, 0);
                }

            // ex values for this tt (fp32; rows per C-layout row = q+8g+4half+32mt)
            float exv[2][4][4];
#pragma unroll
            for (int mt = 0; mt < 2; mt++)
#pragma unroll
                for (int g = 0; g < 4; g++) {
                    int a0 = 32 * mt + 8 * g + 4 * half;
                    int pos = ((a0 >> 2) + tt) & 15;
                    float4 q = *(const float4*)&exbuf[tt * XSTF + pos * 4];
                    exv[mt][g][0] = q.x; exv[mt][g][1] = q.y;
                    exv[mt][g][2] = q.z; exv[mt][g][3] = q.w;
                }

            float v00 = rdlanef(acc[0][0], 0);
            float e0 = rdlanef(exv[0][0][0], 0);
            float sc = v00 * e0;
            float r = frcp(sc);
            ls += flog2(sc);

            // scale + convert + in-place write (Ubuf[col*UST + row])
#pragma unroll
            for (int mt = 0; mt < 2; mt++)
#pragma unroll
                for (int nt = 0; nt < 2; nt++) {
                    int c = l31 + 32 * nt;
#pragma unroll
                    for (int g = 0; g < 4; g++) {
                        int a0 = 32 * mt + 8 * g + 4 * half;
                        const f32x16& A = acc[mt * 2 + nt];
                        unsigned int w0 = (unsigned)bf16bits(A[4 * g + 0] * exv[mt][g][0] * r) |
                                          ((unsigned)bf16bits(A[4 * g + 1] * exv[mt][g][1] * r) << 16);
                        unsigned int w1 = (unsigned)bf16bits(A[4 * g + 2] * exv[mt][g][2] * r) |
                                          ((unsigned)bf16bits(A[4 * g + 3] * exv[mt][g][3] * r) << 16);
                        *(uint2*)&Ubuf[c * UST + a0] = make_uint2(w0, w1);
                    }
                }
        }
    }

    // write U (row-major [a][c], 64x64 bf16); lane = row a
    bf16_t* Uo = ws_u + ((size_t)(b * NSEG + s)) * 4096;
#pragma unroll
    for (int c8 = 0; c8 < 8; c8++) {
        unsigned int w[4];
#pragma unroll
        for (int q = 0; q < 4; q++) {
            int c = c8 * 8 + q * 2;
            unsigned short lo = __builtin_bit_cast(unsigned short, Ubuf[(c)*UST + lane]);
            unsigned short hi = __builtin_bit_cast(unsigned short, Ubuf[(c + 1) * UST + lane]);
            w[q] = (unsigned)lo | ((unsigned)hi << 16);
        }
        *(uint4*)&Uo[lane * 64 + c8 * 8] = make_uint4(w[0], w[1], w[2], w[3]);
    }
    if (lane == 0) ws_ls[b * NSEG + s] = ls;
}

// ---------------- stage 2: chain NSEG segment matrices, apply q0, logsumexp ----------------
__global__ __launch_bounds__(64) void stage2_kernel(
    const float* __restrict__ y_pred, const bf16_t* __restrict__ ws_u,
    const float* __restrict__ ws_ls, float* __restrict__ out) {
    const int b = blockIdx.x;
    const int lane = threadIdx.x;
    const int half = lane >> 5;
    const int l31 = lane & 31;

    __shared__ __align__(16) bf16_t Ubuf[64 * UST];

    // W = I
    {
        uint2* col = (uint2*)&Ubuf[lane * UST];
#pragma unroll
        for (int i = 0; i < 13; i++) col[i] = make_uint2(0, 0);
    }
    __syncthreads();
    if (lane < KK) Ubuf[lane * UST + lane] = (bf16_t)1.0f;

    f32x16 z16;
#pragma unroll
    for (int r = 0; r < 16; r++) z16[r] = 0.0f;

    float ls2 = 0.0f;
    for (int s2 = 0; s2 < NSEG; s2++) {   // ascending: W <- U_s * W
        const bf16_t* Us = ws_u + ((size_t)(b * NSEG + s2)) * 4096;
        bf16x8 afrag[2][3];
#pragma unroll
        for (int mt = 0; mt < 2; mt++) {
            int m = l31 + 32 * mt;
#pragma unroll
            for (int ks = 0; ks < 3; ks++) {
                uint4 q = *(const uint4*)&Us[m * 64 + ks * 16 + half * 8];
                afrag[mt][ks] = __builtin_bit_cast(bf16x8, q);
            }
        }
        bf16x8 bfrag[3][2];
#pragma unroll
        for (int ks = 0; ks < 3; ks++)
#pragma unroll
            for (int nt = 0; nt < 2; nt++) {
                int n = l31 + 32 * nt;
                const bf16_t* p = &Ubuf[n * UST + ks * 16 + half * 8];
                uint2 lo = *(const uint2*)p;
                uint2 hi = *(const uint2*)(p + 4);
                uint4 q = make_uint4(lo.x, lo.y, hi.x, hi.y);
                bfrag[ks][nt] = __builtin_bit_cast(bf16x8, q);
            }

        f32x16 acc[4];
#pragma unroll
        for (int mt = 0; mt < 2; mt++)
#pragma unroll
            for (int nt = 0; nt < 2; nt++) {
                f32x16 a0 = __builtin_amdgcn_mfma_f32_32x32x16_bf16(afrag[mt][0], bfrag[0][nt], z16, 0, 0, 0);
                a0 = __builtin_amdgcn_mfma_f32_32x32x16_bf16(afrag[mt][1], bfrag[1][nt], a0, 0, 0, 0);
                acc[mt * 2 + nt] = __builtin_amdgcn_mfma_f32_32x32x16_bf16(afrag[mt][2], bfrag[2][nt], a0, 0, 0, 0);
            }

        float v00 = rdlanef(acc[0][0], 0);
        float r = frcp(v00);
        ls2 += flog2(v00);

#pragma unroll
        for (int mt = 0; mt < 2; mt++)
#pragma unroll
            for (int nt = 0; nt < 2; nt++) {
                int c = l31 + 32 * nt;
#pragma unroll
                for (int g = 0; g < 4; g++) {
                    int a0 = 32 * mt + 8 * g + 4 * half;
                    const f32x16& A = acc[mt * 2 + nt];
                    unsigned int w0 = (unsigned)bf16bits(A[4 * g + 0] * r) |
                                      ((unsigned)bf16bits(A[4 * g + 1] * r) << 16);
                    unsigned int w1 = (unsigned)bf16bits(A[4 * g + 2] * r) |
                                      ((unsigned)bf16bits(A[4 * g + 3] * r) << 16);
                    *(uint2*)&Ubuf[c * UST + a0] = make_uint2(w0, w1);
                }
            }
    }

    // total log2 scale
    float lsv = (lane < NSEG) ? ws_ls[b * NSEG + lane] : 0.0f;
#pragma unroll
    for (int off = 32; off; off >>= 1) lsv += __shfl_xor(lsv, off);
    float L = lsv + ls2;

    // q0 from t=0 row (mask applied as in reference)
    float x0 = (lane < KK) ? y_pred[(size_t)b * TT * KK + lane] : 0.0f;
    bool ok0 = (lane >= KK) || (x0 > -1e6f);
    bool m0 = (__ballot(ok0) == ~0ull);
    float xeff = (lane < KK) ? (m0 ? x0 : 0.0f) : 0.0f;
    float c0 = rdlanef(xeff, 0);
    float q0 = (lane < KK) ? fexp(xeff - c0) : 0.0f;

    // p[a] = sum_c W[a][c] * q0[c]
    float p = 0.0f;
    for (int c = 0; c < KK; c++) {
        float qc = rdlanef(q0, c);
        float wv = bfbits2f((unsigned)__builtin_bit_cast(unsigned short, Ubuf[c * UST + lane]));
        p = fmaf(wv, qc, p);
    }
#pragma unroll
    for (int off = 32; off; off >>= 1) p += __shfl_xor(p, off);

    if (lane == 0) {
        float ans = c0 + 0.6931471805599453f * (L + flog2(p));
        out[b] += ans;   // scores kernel already deposited -target
    }
}

extern "C" void kernel_launch(void* const* d_in, const int* in_sizes, int n_in,
                              void* d_out, int out_size, void* d_ws, size_t ws_size,
                              hipStream_t stream) {
    const float* y_true = (const float*)d_in[0];
    const float* y_pred = (const float*)d_in[1];
    const float* trans = (const float*)d_in[2];
    float* out = (float*)d_out;

    bf16_t* ws_u = (bf16_t*)d_ws;   // 64*16*4096 bf16 = 8.39 MB
    float* ws_ls = (float*)((char*)d_ws + (size_t)BB * NSEG * 4096 * sizeof(bf16_t));  // +4 KB

    zero_out_kernel<<<1, 64, 0, stream>>>(out);
    scores_kernel<<<dim3(TT / 256, BB), 256, 0, stream>>>(y_true, y_pred, trans, out);
    stage1_kernel<<<dim3(NSEG, BB), 64, 0, stream>>>(y_pred, trans, ws_u, ws_ls);
    stage2_kernel<<<BB, 64, 0, stream>>>(y_pred, ws_u, ws_ls, out);
}

// Round 5
// 317.358 us; speedup vs baseline: 6.7804x; 1.1877x over previous
//
#include <hip/hip_runtime.h>

#define BB 64
#define TT 4096
#define KK 48
#define NSEG 16
#define SEGLEN 256
#define NCH 4           // 4 chunks of 64 steps per segment
#define UST 56          // stage1 Ubuf col stride (bf16): 112 B, mult of 16, 2-way banks
#define UST2 72         // stage2 Ubuf col stride (bf16): 144 B, covers rows 0..63

typedef __bf16 bf16_t;
typedef bf16_t bf16x8 __attribute__((ext_vector_type(8)));
typedef float f32x4 __attribute__((ext_vector_type(4)));
typedef float f32x16 __attribute__((ext_vector_type(16)));

__device__ __forceinline__ float fexp(float x) {   // natural exp
    return __builtin_amdgcn_exp2f(x * 1.4426950408889634f);
}
__device__ __forceinline__ float flog2(float x) { return __builtin_amdgcn_logf(x); }
__device__ __forceinline__ float rdlanef(float v, int l) {
    return __int_as_float(__builtin_amdgcn_readlane(__float_as_int(v), l));
}
__device__ __forceinline__ unsigned int bf16bits(float f) {
    return (unsigned int)__builtin_bit_cast(unsigned short, (bf16_t)f);
}
__device__ __forceinline__ float bf2f(bf16_t h) {
    return __uint_as_float(((unsigned int)__builtin_bit_cast(unsigned short, h)) << 16);
}

__global__ void zero_out_kernel(float* out) {
    if (threadIdx.x < BB) out[threadIdx.x] = 0.0f;
}

// ---------------- scores: point + transition, subtracted into out[b] ----------------
// Fully-coalesced float4 loads; per-float4 partials staged in LDS (stride-13 pad),
// then per-timestep reduction.
__global__ __launch_bounds__(256) void scores_kernel(
    const float* __restrict__ y_true, const float* __restrict__ y_pred,
    const float* __restrict__ trans, float* __restrict__ out) {
    const int b = blockIdx.y;
    const int t0 = blockIdx.x * 256;
    const int tid = threadIdx.x;

    __shared__ float sdot[3328];   // 3072 + 256 pad (stride 13 per timestep)
    __shared__ float slab[3328];
    __shared__ float spmin[3328];
    __shared__ float msk_s[257];
    __shared__ int lab_s[257];

    const float4* yt4 = (const float4*)(y_true + ((size_t)b * TT + t0) * KK);
    const float4* yp4 = (const float4*)(y_pred + ((size_t)b * TT + t0) * KK);

#pragma unroll
    for (int kk = 0; kk < 12; kk++) {
        int f = tid + 256 * kk;
        float4 a = yt4[f];
        float4 p = yp4[f];
        float d = fmaf(a.x, p.x, fmaf(a.y, p.y, fmaf(a.z, p.z, a.w * p.w)));
        float e0 = (float)(4 * (f % 12));
        float lb = fmaf(a.x, e0, fmaf(a.y, e0 + 1.0f, fmaf(a.z, e0 + 2.0f, a.w * (e0 + 3.0f))));
        float pm = fminf(fminf(p.x, p.y), fminf(p.z, p.w));
        int pf = f + f / 12;
        sdot[pf] = d; slab[pf] = lb; spmin[pf] = pm;
    }

    if (tid == 0) {
        if (t0 + 256 < TT) {
            const float4* at = (const float4*)(y_true + ((size_t)b * TT + t0 + 256) * KK);
            const float4* pt = (const float4*)(y_pred + ((size_t)b * TT + t0 + 256) * KK);
            float lb = 0.0f, pm = 1e30f;
#pragma unroll
            for (int g = 0; g < 12; g++) {
                float4 a = at[g]; float4 p = pt[g];
                float e0 = (float)(4 * g);
                lb = fmaf(a.x, e0, fmaf(a.y, e0 + 1.0f, fmaf(a.z, e0 + 2.0f, fmaf(a.w, e0 + 3.0f, lb))));
                pm = fminf(pm, fminf(fminf(p.x, p.y), fminf(p.z, p.w)));
            }
            lab_s[256] = (int)(lb + 0.5f);
            msk_s[256] = (pm > -1e6f) ? 1.0f : 0.0f;
        } else {
            lab_s[256] = 0; msk_s[256] = 0.0f;
        }
    }
    __syncthreads();

    float d = 0.0f, lb = 0.0f, pm = 1e30f;
#pragma unroll
    for (int j = 0; j < 12; j++) {
        int pf = 13 * tid + j;
        d += sdot[pf]; lb += slab[pf]; pm = fminf(pm, spmin[pf]);
    }
    msk_s[tid] = (pm > -1e6f) ? 1.0f : 0.0f;
    lab_s[tid] = (int)(lb + 0.5f);
    __syncthreads();

    const float m = msk_s[tid];
    float contrib = m * d;
    int t = t0 + tid;
    if (t < TT - 1) {
        contrib += m * msk_s[tid + 1] * trans[lab_s[tid] * KK + lab_s[tid + 1]];
    }
#pragma unroll
    for (int off = 32; off; off >>= 1) contrib += __shfl_xor(contrib, off);
    if ((tid & 63) == 0) atomicAdd(&out[b], -contrib);
}

// ---------------- stage 1: per-(b,segment) matrix product, 3 waves x 16 cols ----------------
// Per wave: cols [16w,16w+16) of U (= Seg^T). Per step: D = E^T*U (3x m-tiles of
// 16x16x32 MFMA, K=48 padded to 64), row-scale by ex_t, pow2 rescale (exact int ls).
// Waves reconcile scales at the end via ldexp (exact).
__global__ __launch_bounds__(192) void stage1_kernel(
    const float* __restrict__ y_pred, const float* __restrict__ trans,
    bf16_t* __restrict__ ws_u, int* __restrict__ ws_ls) {
    const int s = blockIdx.x, b = blockIdx.y;
    const int tid = threadIdx.x;
    const int w = tid >> 6;         // wave 0..2
    const int lane = tid & 63;
    const int q = lane >> 4;        // 0..3
    const int n = lane & 15;        // 0..15
    const int ncol = 16 * w + n;    // this wave's global column

    __shared__ __align__(16) bf16_t Ubuf[48 * UST + 32];      // 2720 elems
    __shared__ __align__(16) float4 exb[2][12 * 64];          // [buf][granule*64 + row]
    __shared__ unsigned long long pb[2][4];                   // partial ballots per wave
    __shared__ int lsb[4];

    // A fragments: E^T zero-padded in K. A[m][k]: m = 16*mt + n, k = 32*ks + 8*q + j.
    bf16x8 afrag[3][2];
#pragma unroll
    for (int mt = 0; mt < 3; mt++) {
#pragma unroll
        for (int ks = 0; ks < 2; ks++) {
            bf16x8 f;
#pragma unroll
            for (int j = 0; j < 8; j++) {
                int m = 16 * mt + n;
                int k = 32 * ks + 8 * q + j;
                float v = (k < KK) ? fexp(trans[k * KK + m]) : 0.0f;
                f[j] = (bf16_t)v;
            }
            afrag[mt][ks] = f;
        }
    }

    // zero Ubuf, then set identity diag
    {
        uint4* p = (uint4*)Ubuf;
        for (int i = tid; i < (48 * UST + 32) / 8; i += 192) p[i] = make_uint4(0, 0, 0, 0);
    }
    __syncthreads();
    if (tid < KK) Ubuf[tid * UST + tid] = (bf16_t)1.0f;

    // stage chunk c (64 steps) into exb[buf]; thread (w,lane) covers granules 4w..4w+3 of row `lane`
    auto stage = [&](int c, int buf) {
        const float* xr = y_pred + (((size_t)b * TT + s * SEGLEN + c * 64 + lane) * KK) + 16 * w;
        float4 v0 = *(const float4*)(xr + 0);
        float4 v1 = *(const float4*)(xr + 4);
        float4 v2 = *(const float4*)(xr + 8);
        float4 v3 = *(const float4*)(xr + 12);
        float pm = fminf(fminf(fminf(v0.x, v0.y), fminf(v0.z, v0.w)),
                         fminf(fminf(fminf(v1.x, v1.y), fminf(v1.z, v1.w)),
                               fminf(fminf(fminf(v2.x, v2.y), fminf(v2.z, v2.w)),
                                     fminf(fminf(v3.x, v3.y), fminf(v3.z, v3.w)))));
        unsigned long long bal = __ballot(pm > -1e6f);
        if (lane == 0) pb[buf][w] = bal;
        exb[buf][(4 * w + 0) * 64 + lane] = make_float4(fexp(v0.x), fexp(v0.y), fexp(v0.z), fexp(v0.w));
        exb[buf][(4 * w + 1) * 64 + lane] = make_float4(fexp(v1.x), fexp(v1.y), fexp(v1.z), fexp(v1.w));
        exb[buf][(4 * w + 2) * 64 + lane] = make_float4(fexp(v2.x), fexp(v2.y), fexp(v2.z), fexp(v2.w));
        exb[buf][(4 * w + 3) * 64 + lane] = make_float4(fexp(v3.x), fexp(v3.y), fexp(v3.z), fexp(v3.w));
    };

    stage(0, 0);
    __syncthreads();

    const bf16_t* bptr0 = &Ubuf[ncol * UST + 8 * q];        // B ks=0: rows 8q..8q+7
    const bf16_t* bptr1 = &Ubuf[ncol * UST + 32 + 8 * q];   // B ks=1: rows 32+8q.. (pad rows x A-zeros)
    bf16_t* wp0 = &Ubuf[ncol * UST + 0 + 4 * q];
    bf16_t* wp1 = &Ubuf[ncol * UST + 16 + 4 * q];
    bf16_t* wp2 = &Ubuf[ncol * UST + 32 + 4 * q];

    f32x4 z4 = {0.0f, 0.0f, 0.0f, 0.0f};
    int ls = 0;

    for (int ch = 0; ch < NCH; ch++) {
        if (ch + 1 < NCH) stage(ch + 1, (ch + 1) & 1);
        unsigned long long mk = pb[ch & 1][0] & pb[ch & 1][1] & pb[ch & 1][2];
        const float4* exc = &exb[ch & 1][0];
        const int tt0 = (s == 0 && ch == 0) ? 1 : 0;
        for (int tt = tt0; tt < 64; tt++) {
            if (!((mk >> tt) & 1ull)) continue;

            bf16x8 bf0 = __builtin_bit_cast(bf16x8, *(const uint4*)bptr0);
            bf16x8 bf1 = __builtin_bit_cast(bf16x8, *(const uint4*)bptr1);

            f32x4 acc0 = __builtin_amdgcn_mfma_f32_16x16x32_bf16(afrag[0][0], bf0, z4, 0, 0, 0);
            acc0 = __builtin_amdgcn_mfma_f32_16x16x32_bf16(afrag[0][1], bf1, acc0, 0, 0, 0);
            f32x4 acc1 = __builtin_amdgcn_mfma_f32_16x16x32_bf16(afrag[1][0], bf0, z4, 0, 0, 0);
            acc1 = __builtin_amdgcn_mfma_f32_16x16x32_bf16(afrag[1][1], bf1, acc1, 0, 0, 0);
            f32x4 acc2 = __builtin_amdgcn_mfma_f32_16x16x32_bf16(afrag[2][0], bf0, z4, 0, 0, 0);
            acc2 = __builtin_amdgcn_mfma_f32_16x16x32_bf16(afrag[2][1], bf1, acc2, 0, 0, 0);

            float4 ex0 = exc[(0 * 4 + q) * 64 + tt];   // ex for rows 4q..4q+3 (+16*mt)
            float4 ex1 = exc[(1 * 4 + q) * 64 + tt];
            float4 ex2 = exc[(2 * 4 + q) * 64 + tt];

            float v00 = rdlanef(acc0[0], 0);
            float e00 = rdlanef(ex0.x, 0);
            float sc = v00 * e00;                       // new U[0][16w] pre-scale, > 0
            int k = (int)(__float_as_uint(sc) >> 23) - 127;
            float r = __uint_as_float((unsigned int)(127 - k) << 23);   // 2^-k exact
            ls += k;

            {
                float o0 = acc0[0] * (ex0.x * r), o1 = acc0[1] * (ex0.y * r);
                float o2 = acc0[2] * (ex0.z * r), o3 = acc0[3] * (ex0.w * r);
                *(uint2*)wp0 = make_uint2(bf16bits(o0) | (bf16bits(o1) << 16),
                                          bf16bits(o2) | (bf16bits(o3) << 16));
            }
            {
                float o0 = acc1[0] * (ex1.x * r), o1 = acc1[1] * (ex1.y * r);
                float o2 = acc1[2] * (ex1.z * r), o3 = acc1[3] * (ex1.w * r);
                *(uint2*)wp1 = make_uint2(bf16bits(o0) | (bf16bits(o1) << 16),
                                          bf16bits(o2) | (bf16bits(o3) << 16));
            }
            {
                float o0 = acc2[0] * (ex2.x * r), o1 = acc2[1] * (ex2.y * r);
                float o2 = acc2[2] * (ex2.z * r), o3 = acc2[3] * (ex2.w * r);
                *(uint2*)wp2 = make_uint2(bf16bits(o0) | (bf16bits(o1) << 16),
                                          bf16bits(o2) | (bf16bits(o3) << 16));
            }
        }
        __syncthreads();
    }

    // reconcile per-wave scales (exact pow2), write 64x64 block (rows>=48 zero)
    if (lane == 0) lsb[w] = ls;
    __syncthreads();
    const int dl = ls - lsb[0];
    bf16_t* Uo = ws_u + ((size_t)(b * NSEG + s)) * 4096;
    unsigned int wd[8];
    if (lane < KK) {
#pragma unroll
        for (int j = 0; j < 8; j++) {
            float f0 = ldexpf(bf2f(Ubuf[(16 * w + 2 * j) * UST + lane]), dl);
            float f1 = ldexpf(bf2f(Ubuf[(16 * w + 2 * j + 1) * UST + lane]), dl);
            wd[j] = bf16bits(f0) | (bf16bits(f1) << 16);
        }
    } else {
#pragma unroll
        for (int j = 0; j < 8; j++) wd[j] = 0;
    }
    *(uint4*)(Uo + (size_t)lane * 64 + 16 * w) = make_uint4(wd[0], wd[1], wd[2], wd[3]);
    *(uint4*)(Uo + (size_t)lane * 64 + 16 * w + 8) = make_uint4(wd[4], wd[5], wd[6], wd[7]);
    if (tid == 0) ws_ls[b * NSEG + s] = ls;   // wave-0 scale (others folded in)
}

// ---------------- stage 2: chain NSEG segment matrices, apply q0, logsumexp ----------------
__global__ __launch_bounds__(64) void stage2_kernel(
    const float* __restrict__ y_pred, const bf16_t* __restrict__ ws_u,
    const int* __restrict__ ws_ls, float* __restrict__ out) {
    const int b = blockIdx.x;
    const int lane = threadIdx.x;
    const int half = lane >> 5;
    const int l31 = lane & 31;

    __shared__ __align__(16) bf16_t Ub[64 * UST2];   // 4608 elems

    for (int i = lane; i < 64 * UST2 / 8; i += 64) ((uint4*)Ub)[i] = make_uint4(0, 0, 0, 0);
    if (lane < KK) Ub[lane * UST2 + lane] = (bf16_t)1.0f;   // same-wave ds ordering

    f32x16 z16;
#pragma unroll
    for (int r = 0; r < 16; r++) z16[r] = 0.0f;

    int ls2 = 0;
    for (int s2 = 0; s2 < NSEG; s2++) {   // W <- U_s * W
        const bf16_t* Us = ws_u + ((size_t)(b * NSEG + s2)) * 4096;
        bf16x8 af[2][3];
#pragma unroll
        for (int mt = 0; mt < 2; mt++)
#pragma unroll
            for (int ks = 0; ks < 3; ks++)
                af[mt][ks] = __builtin_bit_cast(bf16x8,
                    *(const uint4*)&Us[(size_t)(l31 + 32 * mt) * 64 + 16 * ks + 8 * half]);
        bf16x8 bg[3][2];
#pragma unroll
        for (int ks = 0; ks < 3; ks++)
#pragma unroll
            for (int nt = 0; nt < 2; nt++)
                bg[ks][nt] = __builtin_bit_cast(bf16x8,
                    *(const uint4*)&Ub[(l31 + 32 * nt) * UST2 + 16 * ks + 8 * half]);

        f32x16 acc[4];
#pragma unroll
        for (int mt = 0; mt < 2; mt++)
#pragma unroll
            for (int nt = 0; nt < 2; nt++) {
                f32x16 a0 = __builtin_amdgcn_mfma_f32_32x32x16_bf16(af[mt][0], bg[0][nt], z16, 0, 0, 0);
                a0 = __builtin_amdgcn_mfma_f32_32x32x16_bf16(af[mt][1], bg[1][nt], a0, 0, 0, 0);
                acc[mt * 2 + nt] = __builtin_amdgcn_mfma_f32_32x32x16_bf16(af[mt][2], bg[2][nt], a0, 0, 0, 0);
            }

        float v00 = rdlanef(acc[0][0], 0);
        int k = (int)(__float_as_uint(v00) >> 23) - 127;
        float r = __uint_as_float((unsigned int)(127 - k) << 23);
        ls2 += k;

#pragma unroll
        for (int mt = 0; mt < 2; mt++)
#pragma unroll
            for (int nt = 0; nt < 2; nt++) {
                int c = l31 + 32 * nt;
#pragma unroll
                for (int g = 0; g < 4; g++) {
                    int a0 = 32 * mt + 8 * g + 4 * half;
                    const f32x16& A = acc[mt * 2 + nt];
                    unsigned int w0 = bf16bits(A[4 * g + 0] * r) | (bf16bits(A[4 * g + 1] * r) << 16);
                    unsigned int w1 = bf16bits(A[4 * g + 2] * r) | (bf16bits(A[4 * g + 3] * r) << 16);
                    *(uint2*)&Ub[c * UST2 + a0] = make_uint2(w0, w1);
                }
            }
    }

    int lsum = (lane < NSEG) ? ws_ls[b * NSEG + lane] : 0;
#pragma unroll
    for (int off = 32; off; off >>= 1) lsum += __shfl_xor(lsum, off);
    float L = (float)(lsum + ls2);

    // q0 from t=0 row
    float x0 = (lane < KK) ? y_pred[(size_t)b * TT * KK + lane] : 0.0f;
    bool ok0 = (lane >= KK) || (x0 > -1e6f);
    bool m0 = (__ballot(ok0) == ~0ull);
    float xeff = (lane < KK) ? (m0 ? x0 : 0.0f) : 0.0f;
    float c0 = rdlanef(xeff, 0);
    float q0 = (lane < KK) ? fexp(xeff - c0) : 0.0f;

    float p = 0.0f;
    for (int c = 0; c < KK; c++) {
        float qc = rdlanef(q0, c);
        p = fmaf(bf2f(Ub[c * UST2 + lane]), qc, p);
    }
#pragma unroll
    for (int off = 32; off; off >>= 1) p += __shfl_xor(p, off);

    if (lane == 0) {
        out[b] += c0 + 0.6931471805599453f * (L + flog2(p));
    }
}

extern "C" void kernel_launch(void* const* d_in, const int* in_sizes, int n_in,
                              void* d_out, int out_size, void* d_ws, size_t ws_size,
                              hipStream_t stream) {
    const float* y_true = (const float*)d_in[0];
    const float* y_pred = (const float*)d_in[1];
    const float* trans = (const float*)d_in[2];
    float* out = (float*)d_out;

    bf16_t* ws_u = (bf16_t*)d_ws;   // 64*16*4096 bf16 = 8.39 MB
    int* ws_ls = (int*)((char*)d_ws + (size_t)BB * NSEG * 4096 * sizeof(bf16_t));  // +4 KB

    zero_out_kernel<<<1, 64, 0, stream>>>(out);
    scores_kernel<<<dim3(TT / 256, BB), 256, 0, stream>>>(y_true, y_pred, trans, out);
    stage1_kernel<<<dim3(NSEG, BB), 192, 0, stream>>>(y_pred, trans, ws_u, ws_ls);
    stage2_kernel<<<BB, 64, 0, stream>>>(y_pred, ws_u, ws_ls, out);
}